// Round 1
// baseline (148.234 us; speedup 1.0000x reference)
//
#include <hip/hip_runtime.h>

#define GRIDN 256

// Per-dimension: replicate jnp.searchsorted(p, c, side='left') then clip,
// using arithmetic guess for the uniform axis + exact fixup against p[].
__device__ __forceinline__ void dim_interp(float c, const float* __restrict__ p,
                                           int& il, int& ir, float& dl, float& dr) {
    const float SCALE = 0.005f;
    const float OFFSET = -0.64f;
    float t = (c - OFFSET) * (1.0f / SCALE);
    int i = (int)ceilf(t);
    i = min(max(i, 0), GRIDN - 1);
    // exact searchsorted-left semantics: smallest i with p[i] >= c (clipped to N-1)
    while (i < GRIDN - 1 && p[i] < c) ++i;
    while (i > 0 && p[i - 1] >= c) --i;
    ir = i;
    il = max(i - 1, 0);
    dl = fmaxf(c - p[il], 0.0f);
    dr = fmaxf(p[ir] - c, 0.0f);
    if (dl == 0.0f && dr == 0.0f) { dl = 1.0f; dr = 1.0f; }
}

__global__ void trilerp_kernel(const float* __restrict__ x,
                               const float* __restrict__ values,
                               const float* __restrict__ px,
                               const float* __restrict__ py,
                               const float* __restrict__ pz,
                               float* __restrict__ out, int K) {
    int i = blockIdx.x * blockDim.x + threadIdx.x;
    if (i >= K) return;

    float cx = x[3 * i + 0];
    float cy = x[3 * i + 1];
    float cz = x[3 * i + 2];

    int ixl, ixr, iyl, iyr, izl, izr;
    float dxl, dxr, dyl, dyr, dzl, dzr;
    dim_interp(cx, px, ixl, ixr, dxl, dxr);
    dim_interp(cy, py, iyl, iyr, dyl, dyr);
    dim_interp(cz, pz, izl, izr, dzl, dzr);

    // values[ix][iy][iz], z fastest. 256 grid -> shifts.
    int bxl = ixl << 16, bxr = ixr << 16;
    int byl = iyl << 8,  byr = iyr << 8;

    // onoff: 0 -> left index with weight d*r ; 1 -> right index with weight d*l
    float v000 = values[bxl + byl + izl];
    float v001 = values[bxl + byl + izr];
    float v010 = values[bxl + byr + izl];
    float v011 = values[bxl + byr + izr];
    float v100 = values[bxr + byl + izl];
    float v101 = values[bxr + byl + izr];
    float v110 = values[bxr + byr + izl];
    float v111 = values[bxr + byr + izr];

    float num =
        v000 * (dxr * dyr * dzr) +
        v001 * (dxr * dyr * dzl) +
        v010 * (dxr * dyl * dzr) +
        v011 * (dxr * dyl * dzl) +
        v100 * (dxl * dyr * dzr) +
        v101 * (dxl * dyr * dzl) +
        v110 * (dxl * dyl * dzr) +
        v111 * (dxl * dyl * dzl);

    float den = (dxl + dxr) * (dyl + dyr) * (dzl + dzr);
    out[i] = num / den;
}

extern "C" void kernel_launch(void* const* d_in, const int* in_sizes, int n_in,
                              void* d_out, int out_size, void* d_ws, size_t ws_size,
                              hipStream_t stream) {
    const float* x      = (const float*)d_in[0];
    const float* values = (const float*)d_in[1];
    const float* px     = (const float*)d_in[2];
    const float* py     = (const float*)d_in[3];
    const float* pz     = (const float*)d_in[4];
    float* out = (float*)d_out;

    int K = in_sizes[0] / 3;
    int block = 256;
    int grid = (K + block - 1) / block;
    trilerp_kernel<<<grid, block, 0, stream>>>(x, values, px, py, pz, out, K);
}